// Round 11
// baseline (423.719 us; speedup 1.0000x reference)
//
#include <hip/hip_runtime.h>

#define N_NODES 100000
#define E_EDGES 1600000
#define EP      (E_EDGES + N_NODES)   // edges + self loops = 1,700,000
#define P_CAND  262144
#define IN_C    128
#define HID     64
#define NEG_SLOPE 0.2f

#define NBIN  196            // ceil(100000/512) bins of 512 nodes
#define NB2   256            // blocks for hist/scatterbin
#define EPB   ((EP + NB2 - 1) / NB2)   // 6641 edges per block
#define NTOT  (NBIN * NB2)   // 50176 (= 1024*49)

typedef _Float16 half4v __attribute__((ext_vector_type(4)));
typedef _Float16 half8v __attribute__((ext_vector_type(8)));
typedef float    float4v __attribute__((ext_vector_type(4)));

// ---------------- CSR build: deterministic 2-level counting sort ----------------

__global__ __launch_bounds__(256) void hist_kernel(const int* __restrict__ ei,
                                                   int* __restrict__ hist) {
    __shared__ int lh[NBIN];
    for (int t = threadIdx.x; t < NBIN; t += 256) lh[t] = 0;
    __syncthreads();
    int start = blockIdx.x * EPB;
    int end = min(start + EPB, EP);
    for (int i = start + threadIdx.x; i < end; i += 256) {
        int dst = (i < E_EDGES) ? ei[E_EDGES + i] : (i - E_EDGES);
        atomicAdd(&lh[dst >> 9], 1);
    }
    __syncthreads();
    for (int t = threadIdx.x; t < NBIN; t += 256) hist[t * NB2 + blockIdx.x] = lh[t];
}

__global__ __launch_bounds__(1024) void scan2_kernel(const int* __restrict__ hist,
                                                     int* __restrict__ histS) {
    __shared__ int s[1024];
    int t = threadIdx.x;
    int b0 = t * 49;                       // 1024*49 == 50176
    int sum = 0;
    for (int i = 0; i < 49; i++) sum += hist[b0 + i];
    s[t] = sum;
    __syncthreads();
    for (int d = 1; d < 1024; d <<= 1) {
        int v = (t >= d) ? s[t - d] : 0;
        __syncthreads();
        s[t] += v;
        __syncthreads();
    }
    int run = s[t] - sum;
    for (int i = 0; i < 49; i++) { int hv = hist[b0 + i]; histS[b0 + i] = run; run += hv; }
}

__global__ __launch_bounds__(256) void scatterbin_kernel(const int* __restrict__ ei,
                                                         const int* __restrict__ histS,
                                                         unsigned* __restrict__ binned) {
    __shared__ int cur[NBIN];
    for (int t = threadIdx.x; t < NBIN; t += 256) cur[t] = histS[t * NB2 + blockIdx.x];
    __syncthreads();
    int start = blockIdx.x * EPB;
    int end = min(start + EPB, EP);
    for (int i = start + threadIdx.x; i < end; i += 256) {
        int src, dst;
        if (i < E_EDGES) { src = ei[i]; dst = ei[E_EDGES + i]; }
        else             { src = i - E_EDGES; dst = src; }
        int pos = atomicAdd(&cur[dst >> 9], 1);
        binned[pos] = (unsigned)src | ((unsigned)(dst & 511) << 17);
    }
}

__global__ __launch_bounds__(1024) void binsort_kernel(const unsigned* __restrict__ binned,
                                                       const int* __restrict__ histS,
                                                       int* __restrict__ off,
                                                       int* __restrict__ csr) {
    __shared__ int lh[512];
    __shared__ int lsc[512];
    int b = blockIdx.x, t = threadIdx.x;
    int base = histS[b * NB2];
    int endv = (b == NBIN - 1) ? EP : histS[(b + 1) * NB2];
    if (t < 512) lh[t] = 0;
    __syncthreads();
    for (int i = base + t; i < endv; i += 1024)
        atomicAdd(&lh[binned[i] >> 17], 1);
    __syncthreads();
    if (t < 512) lsc[t] = lh[t];
    __syncthreads();
    for (int d = 1; d < 512; d <<= 1) {
        int v = (t >= d && t < 512) ? lsc[t - d] : 0;
        __syncthreads();
        if (t < 512) lsc[t] += v;
        __syncthreads();
    }
    if (t < 512) {
        int ex = lsc[t] - lh[t];
        int node = b * 512 + t;
        if (node <= N_NODES) off[node] = base + ex;
        lh[t] = base + ex;
    }
    __syncthreads();
    for (int i = base + t; i < endv; i += 1024) {
        unsigned v = binned[i];
        int pos = atomicAdd(&lh[v >> 17], 1);
        csr[pos] = (int)(v & 0x1FFFFu);
    }
}

// ---------------- Weight prep: fp16 transposed copies (L2-resident) ----------------

__global__ __launch_bounds__(256) void prep_kernel(const float* __restrict__ W1,
                                                   const float* __restrict__ W2,
                                                   _Float16* __restrict__ W1T,
                                                   _Float16* __restrict__ W2T) {
    int idx = blockIdx.x * 256 + threadIdx.x;
    if (idx < 128 * 128) {
        int col = idx >> 7, k = idx & 127;
        W1T[idx] = (_Float16)W1[k * 128 + col];
    } else if (idx < 128 * 128 + 64 * 128) {
        int i2 = idx - 128 * 128;
        int col = i2 >> 7, k = i2 & 127;
        W2T[i2] = (_Float16)W2[k * 64 + col];
    }
}

// ---------------- Layer 1 GEMM: MFMA 16x16x32_f16, 64 nodes/block ----------------

__global__ __launch_bounds__(256) void gemm1_kernel(
        const float* __restrict__ x, const _Float16* __restrict__ W1T,
        const float* __restrict__ att_src1, const float* __restrict__ att_dst1,
        _Float16* __restrict__ xw1h, float* __restrict__ as1, float* __restrict__ ad1) {
    __shared__ _Float16 xs[64 * 136];       // [node][k], stride 272 B (16B mult)
    int tid = threadIdx.x;
    int base = blockIdx.x * 64;
#pragma unroll 4
    for (int it = 0; it < 32; ++it) {
        int e = it * 256 + tid;
        int nn = e >> 7, k = e & 127;
        float v = (base + nn < N_NODES) ? x[(size_t)base * 128 + e] : 0.f;
        xs[nn * 136 + k] = (_Float16)v;
    }
    __syncthreads();
    int w = tid >> 6, l = tid & 63;
    int quad = l >> 4, lq = l & 15;
    float4v acc[8];
#pragma unroll
    for (int t = 0; t < 8; t++) acc[t] = (float4v)0.f;
    const _Float16* arow = &xs[(16 * w + lq) * 136];
#pragma unroll
    for (int ks = 0; ks < 4; ++ks) {
        half8v a = *(const half8v*)&arow[ks * 32 + quad * 8];
#pragma unroll
        for (int t = 0; t < 8; t++) {
            half8v b = *(const half8v*)&W1T[(t * 16 + lq) * 128 + ks * 32 + quad * 8];
            acc[t] = __builtin_amdgcn_mfma_f32_16x16x32_f16(a, b, acc[t], 0, 0, 0);
        }
    }
    float s_att[8], d_att[8];
#pragma unroll
    for (int t = 0; t < 8; t++) {
        s_att[t] = att_src1[t * 16 + lq];
        d_att[t] = att_dst1[t * 16 + lq];
    }
#pragma unroll
    for (int r = 0; r < 4; r++) {
        float ps0 = 0.f, ps1 = 0.f, pd0 = 0.f, pd1 = 0.f;
#pragma unroll
        for (int t = 0; t < 4; t++) {
            ps0 = fmaf(acc[t][r], s_att[t], ps0);
            pd0 = fmaf(acc[t][r], d_att[t], pd0);
            ps1 = fmaf(acc[t + 4][r], s_att[t + 4], ps1);
            pd1 = fmaf(acc[t + 4][r], d_att[t + 4], pd1);
        }
#pragma unroll
        for (int m = 8; m >= 1; m >>= 1) {
            ps0 += __shfl_xor(ps0, m); ps1 += __shfl_xor(ps1, m);
            pd0 += __shfl_xor(pd0, m); pd1 += __shfl_xor(pd1, m);
        }
        int n = base + 16 * w + quad * 4 + r;
        if (lq == 0 && n < N_NODES) {
            as1[n * 2] = ps0; as1[n * 2 + 1] = ps1;
            ad1[n * 2] = pd0; ad1[n * 2 + 1] = pd1;
        }
    }
    __syncthreads();
#pragma unroll
    for (int t = 0; t < 8; t++)
#pragma unroll
        for (int r = 0; r < 4; r++)
            xs[(16 * w + quad * 4 + r) * 136 + t * 16 + lq] = (_Float16)acc[t][r];
    __syncthreads();
    int node = tid >> 2, seg = tid & 3;
    if (base + node < N_NODES) {
#pragma unroll
        for (int i = 0; i < 4; i++) {
            half8v vv = *(const half8v*)&xs[node * 136 + seg * 32 + i * 8];
            *(half8v*)&xw1h[(size_t)(base + node) * 128 + seg * 32 + i * 8] = vv;
        }
    }
}

// ---- Layer 1 aggregation: 16-lane group per edge, no shuffles, fused fsum ----

__global__ __launch_bounds__(256) void agg1_kernel(
        const int* __restrict__ off, const int* __restrict__ csr_src,
        const float* __restrict__ as1, const float* __restrict__ ad1,
        const _Float16* __restrict__ xw1h, const float* __restrict__ b1,
        float* __restrict__ h) {
    int wv = threadIdx.x >> 6, lane = threadIdx.x & 63;
    int n = blockIdx.x * 4 + wv;
    if (n >= N_NODES) return;
    int s = off[n], e = off[n + 1];
    float adn0 = ad1[2 * n], adn1 = ad1[2 * n + 1];
    int g = lane >> 4, q = lane & 15;       // group=edge slot; cols 8q..8q+7 (q<8:head0)
    float acc[8];
#pragma unroll
    for (int i = 0; i < 8; i++) acc[i] = 0.f;
    float fsum = 0.f;
    for (int j = s + g; j < e; j += 4) {
        int src = csr_src[j];               // 16 lanes same dword; 4 dwords/wave
        float2 a = *(const float2*)&as1[2 * src];
        float e0 = a.x + adn0; e0 = e0 > 0.f ? e0 : NEG_SLOPE * e0;
        float e1 = a.y + adn1; e1 = e1 > 0.f ? e1 : NEG_SLOPE * e1;
        float f = __expf(q >= 8 ? e1 : e0);
        fsum += f;
        half8v hv = *(const half8v*)&xw1h[(size_t)src * 128 + 8 * q];
#pragma unroll
        for (int i = 0; i < 8; i++) acc[i] = fmaf((float)hv[i], f, acc[i]);
    }
#pragma unroll
    for (int m = 32; m >= 16; m >>= 1) {
#pragma unroll
        for (int i = 0; i < 8; i++) acc[i] += __shfl_xor(acc[i], m);
        fsum += __shfl_xor(fsum, m);
    }
    if (lane < 16) {
        int c = 8 * q;
        float4 ba = *(const float4*)&b1[c];
        float4 bb = *(const float4*)&b1[c + 4];
        float4 o0, o1;
        o0.x = acc[0] / fsum + ba.x; o0.y = acc[1] / fsum + ba.y;
        o0.z = acc[2] / fsum + ba.z; o0.w = acc[3] / fsum + ba.w;
        o1.x = acc[4] / fsum + bb.x; o1.y = acc[5] / fsum + bb.y;
        o1.z = acc[6] / fsum + bb.z; o1.w = acc[7] / fsum + bb.w;
        o0.x = o0.x > 0.f ? o0.x : 0.f; o0.y = o0.y > 0.f ? o0.y : 0.f;
        o0.z = o0.z > 0.f ? o0.z : 0.f; o0.w = o0.w > 0.f ? o0.w : 0.f;
        o1.x = o1.x > 0.f ? o1.x : 0.f; o1.y = o1.y > 0.f ? o1.y : 0.f;
        o1.z = o1.z > 0.f ? o1.z : 0.f; o1.w = o1.w > 0.f ? o1.w : 0.f;
        *(float4*)&h[(size_t)n * 128 + c] = o0;
        *(float4*)&h[(size_t)n * 128 + c + 4] = o1;
    }
}

// ---------------- Layer 2 GEMM: MFMA 16x16x32_f16, 64 nodes/block, N=64 ------------

__global__ __launch_bounds__(256) void gemm2_kernel(
        const float* __restrict__ h, const _Float16* __restrict__ W2T,
        const float* __restrict__ att_src2, const float* __restrict__ att_dst2,
        _Float16* __restrict__ xw2h, float* __restrict__ as2, float* __restrict__ ad2) {
    __shared__ _Float16 xs[64 * 136];
    int tid = threadIdx.x;
    int base = blockIdx.x * 64;
#pragma unroll 4
    for (int it = 0; it < 32; ++it) {
        int e = it * 256 + tid;
        int nn = e >> 7, k = e & 127;
        float v = (base + nn < N_NODES) ? h[(size_t)base * 128 + e] : 0.f;
        xs[nn * 136 + k] = (_Float16)v;
    }
    __syncthreads();
    int w = tid >> 6, l = tid & 63;
    int quad = l >> 4, lq = l & 15;
    float4v acc[4];
#pragma unroll
    for (int t = 0; t < 4; t++) acc[t] = (float4v)0.f;
    const _Float16* arow = &xs[(16 * w + lq) * 136];
#pragma unroll
    for (int ks = 0; ks < 4; ++ks) {
        half8v a = *(const half8v*)&arow[ks * 32 + quad * 8];
#pragma unroll
        for (int t = 0; t < 4; t++) {
            half8v b = *(const half8v*)&W2T[(t * 16 + lq) * 128 + ks * 32 + quad * 8];
            acc[t] = __builtin_amdgcn_mfma_f32_16x16x32_f16(a, b, acc[t], 0, 0, 0);
        }
    }
    float s_att[4], d_att[4];
#pragma unroll
    for (int t = 0; t < 4; t++) {
        s_att[t] = att_src2[t * 16 + lq];
        d_att[t] = att_dst2[t * 16 + lq];
    }
#pragma unroll
    for (int r = 0; r < 4; r++) {
        float ps = 0.f, pd = 0.f;
#pragma unroll
        for (int t = 0; t < 4; t++) {
            ps = fmaf(acc[t][r], s_att[t], ps);
            pd = fmaf(acc[t][r], d_att[t], pd);
        }
#pragma unroll
        for (int m = 8; m >= 1; m >>= 1) {
            ps += __shfl_xor(ps, m);
            pd += __shfl_xor(pd, m);
        }
        int n = base + 16 * w + quad * 4 + r;
        if (lq == 0 && n < N_NODES) { as2[n] = ps; ad2[n] = pd; }
    }
    __syncthreads();
#pragma unroll
    for (int t = 0; t < 4; t++)
#pragma unroll
        for (int r = 0; r < 4; r++)
            xs[(16 * w + quad * 4 + r) * 72 + t * 16 + lq] = (_Float16)acc[t][r];
    __syncthreads();
#pragma unroll
    for (int it = 0; it < 2; ++it) {
        int idx = it * 256 + tid;           // 0..511
        int node = idx >> 3, k8 = idx & 7;
        if (base + node < N_NODES) {
            half8v vv = *(const half8v*)&xs[node * 72 + k8 * 8];
            *(half8v*)&xw2h[(size_t)(base + node) * 64 + k8 * 8] = vv;
        }
    }
}

// ---- Layer 2 aggregation: 8-lane group per edge, no shuffles, fused u/v epilogue ----

__global__ __launch_bounds__(256) void agg2_kernel(
        const int* __restrict__ off, const int* __restrict__ csr_src,
        const float* __restrict__ as2, const float* __restrict__ ad2,
        const _Float16* __restrict__ xw2h, const float* __restrict__ b2,
        const float* __restrict__ lw, float* __restrict__ u, float* __restrict__ v) {
    int wv = threadIdx.x >> 6, lane = threadIdx.x & 63;
    int n = blockIdx.x * 4 + wv;
    if (n >= N_NODES) return;
    int s = off[n], e = off[n + 1];
    float adn = ad2[n];
    int g = lane >> 3, q = lane & 7;        // group=edge slot; cols 8q..8q+7
    float acc[8];
#pragma unroll
    for (int i = 0; i < 8; i++) acc[i] = 0.f;
    float fsum = 0.f;
    for (int j = s + g; j < e; j += 8) {
        int src = csr_src[j];               // 8 lanes same dword; 8 dwords/wave
        float a = as2[src];
        float ev = a + adn; ev = ev > 0.f ? ev : NEG_SLOPE * ev;
        float f = __expf(ev);
        fsum += f;
        half8v hv = *(const half8v*)&xw2h[(size_t)src * 64 + 8 * q];
#pragma unroll
        for (int i = 0; i < 8; i++) acc[i] = fmaf((float)hv[i], f, acc[i]);
    }
#pragma unroll
    for (int m = 32; m >= 8; m >>= 1) {
#pragma unroll
        for (int i = 0; i < 8; i++) acc[i] += __shfl_xor(acc[i], m);
        fsum += __shfl_xor(fsum, m);
    }
    int c = 8 * q;
    float pu = 0.f, pv = 0.f;
#pragma unroll
    for (int i = 0; i < 8; i++) {
        float zi = acc[i] / fsum + b2[c + i];
        pu = fmaf(zi, lw[c + i], pu);
        pv = fmaf(zi, lw[64 + c + i], pv);
    }
#pragma unroll
    for (int m = 4; m >= 1; m >>= 1) {
        pu += __shfl_xor(pu, m);
        pv += __shfl_xor(pv, m);
    }
    if (lane == 0) { u[n] = pu; v[n] = pv; }
}

// ---------------- Link decode: out = u[s] + v[d] + lb ----------------

__global__ __launch_bounds__(256) void decode_kernel(
        const int* __restrict__ pos_ei, const int* __restrict__ neg_ei,
        const float* __restrict__ u, const float* __restrict__ v,
        const float* __restrict__ lb, float* __restrict__ out) {
    int idx = blockIdx.x * 256 + threadIdx.x;
    if (idx >= 2 * P_CAND) return;
    const int* ei; int p;
    if (idx < P_CAND) { ei = pos_ei; p = idx; }
    else              { ei = neg_ei; p = idx - P_CAND; }
    int sN = ei[p], dN = ei[P_CAND + p];
    out[idx] = u[sN] + v[dN] + lb[0];
}

// ---------------- launch ----------------

extern "C" void kernel_launch(void* const* d_in, const int* in_sizes, int n_in,
                              void* d_out, int out_size, void* d_ws, size_t ws_size,
                              hipStream_t stream) {
    const float* x        = (const float*)d_in[0];
    const int*   ei       = (const int*)d_in[1];
    const int*   pos_ei   = (const int*)d_in[3];
    const int*   neg_ei   = (const int*)d_in[4];
    const float* W1       = (const float*)d_in[5];
    const float* att_src1 = (const float*)d_in[6];
    const float* att_dst1 = (const float*)d_in[7];
    const float* b1       = (const float*)d_in[8];
    const float* W2       = (const float*)d_in[9];
    const float* att_src2 = (const float*)d_in[10];
    const float* att_dst2 = (const float*)d_in[11];
    const float* b2       = (const float*)d_in[12];
    const float* lw       = (const float*)d_in[13];
    const float* lb       = (const float*)d_in[14];
    float* out = (float*)d_out;

    char* ws = (char*)d_ws;
    size_t o = 0;
    auto alloc = [&](size_t bytes) -> char* {
        char* p = ws + o;
        o += (bytes + 511) & ~(size_t)511;
        return p;
    };
    _Float16* xw1h  = (_Float16*)alloc((size_t)N_NODES * 128 * 2);  // reused: xw2h
    float*    h     = (float*)alloc((size_t)N_NODES * 128 * 4);
    float*    u     = (float*)alloc((size_t)N_NODES * 4);
    float*    v     = (float*)alloc((size_t)N_NODES * 4);
    float*    as1   = (float*)alloc((size_t)N_NODES * 2 * 4);
    float*    ad1   = (float*)alloc((size_t)N_NODES * 2 * 4);
    float*    as2   = (float*)alloc((size_t)N_NODES * 4);
    float*    ad2   = (float*)alloc((size_t)N_NODES * 4);
    int*      off   = (int*)alloc((size_t)(N_NODES + 1) * 4);
    int*      hist  = (int*)alloc((size_t)NTOT * 4);
    int*      histS = (int*)alloc((size_t)NTOT * 4);
    unsigned* binned= (unsigned*)alloc((size_t)EP * 4);
    int*      csr   = (int*)alloc((size_t)EP * 4);
    _Float16* W1T   = (_Float16*)alloc((size_t)128 * 128 * 2);
    _Float16* W2T   = (_Float16*)alloc((size_t)64 * 128 * 2);
    _Float16* xw2h  = xw1h;    // xw1h dead after agg1

    prep_kernel<<<96, 256, 0, stream>>>(W1, W2, W1T, W2T);
    hist_kernel<<<NB2, 256, 0, stream>>>(ei, hist);
    scan2_kernel<<<1, 1024, 0, stream>>>(hist, histS);
    scatterbin_kernel<<<NB2, 256, 0, stream>>>(ei, histS, binned);
    binsort_kernel<<<NBIN, 1024, 0, stream>>>(binned, histS, off, csr);
    gemm1_kernel<<<(N_NODES + 63) / 64, 256, 0, stream>>>(x, W1T, att_src1, att_dst1, xw1h, as1, ad1);
    agg1_kernel<<<(N_NODES + 3) / 4, 256, 0, stream>>>(off, csr, as1, ad1, xw1h, b1, h);
    gemm2_kernel<<<(N_NODES + 63) / 64, 256, 0, stream>>>(h, W2T, att_src2, att_dst2, xw2h, as2, ad2);
    agg2_kernel<<<(N_NODES + 3) / 4, 256, 0, stream>>>(off, csr, as2, ad2, xw2h, b2, lw, u, v);
    decode_kernel<<<(2 * P_CAND + 255) / 256, 256, 0, stream>>>(pos_ei, neg_ei, u, v, lb, out);
}

// Round 12
// 396.924 us; speedup vs baseline: 1.0675x; 1.0675x over previous
//
#include <hip/hip_runtime.h>

#define N_NODES 100000
#define E_EDGES 1600000
#define EP      (E_EDGES + N_NODES)   // edges + self loops = 1,700,000
#define P_CAND  262144
#define IN_C    128
#define HID     64
#define NEG_SLOPE 0.2f

#define NBIN  196            // ceil(100000/512) bins of 512 nodes
#define NB2   256            // blocks for hist/scatterbin
#define EPB   ((EP + NB2 - 1) / NB2)   // 6641 edges per block
#define NTOT  (NBIN * NB2)   // 50176 (= 1024*49)

typedef _Float16 half4v __attribute__((ext_vector_type(4)));
typedef _Float16 half8v __attribute__((ext_vector_type(8)));
typedef float    float4v __attribute__((ext_vector_type(4)));

// ---------------- CSR build: deterministic 2-level counting sort ----------------

__global__ __launch_bounds__(256) void hist_kernel(const int* __restrict__ ei,
                                                   int* __restrict__ hist) {
    __shared__ int lh[NBIN];
    for (int t = threadIdx.x; t < NBIN; t += 256) lh[t] = 0;
    __syncthreads();
    int start = blockIdx.x * EPB;
    int end = min(start + EPB, EP);
    for (int i = start + threadIdx.x; i < end; i += 256) {
        int dst = (i < E_EDGES) ? ei[E_EDGES + i] : (i - E_EDGES);
        atomicAdd(&lh[dst >> 9], 1);
    }
    __syncthreads();
    for (int t = threadIdx.x; t < NBIN; t += 256) hist[t * NB2 + blockIdx.x] = lh[t];
}

__global__ __launch_bounds__(1024) void scan2_kernel(const int* __restrict__ hist,
                                                     int* __restrict__ histS) {
    __shared__ int s[1024];
    int t = threadIdx.x;
    int b0 = t * 49;                       // 1024*49 == 50176
    int sum = 0;
    for (int i = 0; i < 49; i++) sum += hist[b0 + i];
    s[t] = sum;
    __syncthreads();
    for (int d = 1; d < 1024; d <<= 1) {
        int v = (t >= d) ? s[t - d] : 0;
        __syncthreads();
        s[t] += v;
        __syncthreads();
    }
    int run = s[t] - sum;
    for (int i = 0; i < 49; i++) { int hv = hist[b0 + i]; histS[b0 + i] = run; run += hv; }
}

__global__ __launch_bounds__(256) void scatterbin_kernel(const int* __restrict__ ei,
                                                         const int* __restrict__ histS,
                                                         unsigned* __restrict__ binned) {
    __shared__ int cur[NBIN];
    for (int t = threadIdx.x; t < NBIN; t += 256) cur[t] = histS[t * NB2 + blockIdx.x];
    __syncthreads();
    int start = blockIdx.x * EPB;
    int end = min(start + EPB, EP);
    for (int i = start + threadIdx.x; i < end; i += 256) {
        int src, dst;
        if (i < E_EDGES) { src = ei[i]; dst = ei[E_EDGES + i]; }
        else             { src = i - E_EDGES; dst = src; }
        int pos = atomicAdd(&cur[dst >> 9], 1);
        binned[pos] = (unsigned)src | ((unsigned)(dst & 511) << 17);
    }
}

__global__ __launch_bounds__(1024) void binsort_kernel(const unsigned* __restrict__ binned,
                                                       const int* __restrict__ histS,
                                                       int* __restrict__ off,
                                                       int* __restrict__ csr) {
    __shared__ int lh[512];
    __shared__ int lsc[512];
    int b = blockIdx.x, t = threadIdx.x;
    int base = histS[b * NB2];
    int endv = (b == NBIN - 1) ? EP : histS[(b + 1) * NB2];
    if (t < 512) lh[t] = 0;
    __syncthreads();
    for (int i = base + t; i < endv; i += 1024)
        atomicAdd(&lh[binned[i] >> 17], 1);
    __syncthreads();
    if (t < 512) lsc[t] = lh[t];
    __syncthreads();
    for (int d = 1; d < 512; d <<= 1) {
        int v = (t >= d && t < 512) ? lsc[t - d] : 0;
        __syncthreads();
        if (t < 512) lsc[t] += v;
        __syncthreads();
    }
    if (t < 512) {
        int ex = lsc[t] - lh[t];
        int node = b * 512 + t;
        if (node <= N_NODES) off[node] = base + ex;
        lh[t] = base + ex;
    }
    __syncthreads();
    for (int i = base + t; i < endv; i += 1024) {
        unsigned v = binned[i];
        int pos = atomicAdd(&lh[v >> 17], 1);
        csr[pos] = (int)(v & 0x1FFFFu);
    }
}

// ---------------- Weight prep: fp16 transposed copies (L2-resident) ----------------

__global__ __launch_bounds__(256) void prep_kernel(const float* __restrict__ W1,
                                                   const float* __restrict__ W2,
                                                   _Float16* __restrict__ W1T,
                                                   _Float16* __restrict__ W2T) {
    int idx = blockIdx.x * 256 + threadIdx.x;
    if (idx < 128 * 128) {
        int col = idx >> 7, k = idx & 127;
        W1T[idx] = (_Float16)W1[k * 128 + col];
    } else if (idx < 128 * 128 + 64 * 128) {
        int i2 = idx - 128 * 128;
        int col = i2 >> 7, k = i2 & 127;
        W2T[i2] = (_Float16)W2[k * 64 + col];
    }
}

// ---------------- Layer 1 GEMM: MFMA 16x16x32_f16, 64 nodes/block ----------------

__global__ __launch_bounds__(256) void gemm1_kernel(
        const float* __restrict__ x, const _Float16* __restrict__ W1T,
        const float* __restrict__ att_src1, const float* __restrict__ att_dst1,
        _Float16* __restrict__ xw1h, float* __restrict__ as1, float* __restrict__ ad1) {
    __shared__ _Float16 xs[64 * 136];       // [node][k], stride 272 B (16B mult)
    int tid = threadIdx.x;
    int base = blockIdx.x * 64;
#pragma unroll 4
    for (int it = 0; it < 32; ++it) {
        int e = it * 256 + tid;
        int nn = e >> 7, k = e & 127;
        float v = (base + nn < N_NODES) ? x[(size_t)base * 128 + e] : 0.f;
        xs[nn * 136 + k] = (_Float16)v;
    }
    __syncthreads();
    int w = tid >> 6, l = tid & 63;
    int quad = l >> 4, lq = l & 15;
    float4v acc[8];
#pragma unroll
    for (int t = 0; t < 8; t++) acc[t] = (float4v)0.f;
    const _Float16* arow = &xs[(16 * w + lq) * 136];
#pragma unroll
    for (int ks = 0; ks < 4; ++ks) {
        half8v a = *(const half8v*)&arow[ks * 32 + quad * 8];
#pragma unroll
        for (int t = 0; t < 8; t++) {
            half8v b = *(const half8v*)&W1T[(t * 16 + lq) * 128 + ks * 32 + quad * 8];
            acc[t] = __builtin_amdgcn_mfma_f32_16x16x32_f16(a, b, acc[t], 0, 0, 0);
        }
    }
    float s_att[8], d_att[8];
#pragma unroll
    for (int t = 0; t < 8; t++) {
        s_att[t] = att_src1[t * 16 + lq];
        d_att[t] = att_dst1[t * 16 + lq];
    }
#pragma unroll
    for (int r = 0; r < 4; r++) {
        float ps0 = 0.f, ps1 = 0.f, pd0 = 0.f, pd1 = 0.f;
#pragma unroll
        for (int t = 0; t < 4; t++) {
            ps0 = fmaf(acc[t][r], s_att[t], ps0);
            pd0 = fmaf(acc[t][r], d_att[t], pd0);
            ps1 = fmaf(acc[t + 4][r], s_att[t + 4], ps1);
            pd1 = fmaf(acc[t + 4][r], d_att[t + 4], pd1);
        }
#pragma unroll
        for (int m = 8; m >= 1; m >>= 1) {
            ps0 += __shfl_xor(ps0, m); ps1 += __shfl_xor(ps1, m);
            pd0 += __shfl_xor(pd0, m); pd1 += __shfl_xor(pd1, m);
        }
        int n = base + 16 * w + quad * 4 + r;
        if (lq == 0 && n < N_NODES) {
            as1[n * 2] = ps0; as1[n * 2 + 1] = ps1;
            ad1[n * 2] = pd0; ad1[n * 2 + 1] = pd1;
        }
    }
    __syncthreads();
#pragma unroll
    for (int t = 0; t < 8; t++)
#pragma unroll
        for (int r = 0; r < 4; r++)
            xs[(16 * w + quad * 4 + r) * 136 + t * 16 + lq] = (_Float16)acc[t][r];
    __syncthreads();
    int node = tid >> 2, seg = tid & 3;
    if (base + node < N_NODES) {
#pragma unroll
        for (int i = 0; i < 4; i++) {
            half8v vv = *(const half8v*)&xs[node * 136 + seg * 32 + i * 8];
            *(half8v*)&xw1h[(size_t)(base + node) * 128 + seg * 32 + i * 8] = vv;
        }
    }
}

// ---- Layer 1 aggregation (r10 structure): 4 edges/iter, half8 gathers, fp16 h out ----

__global__ __launch_bounds__(256) void agg1_kernel(
        const int* __restrict__ off, const int* __restrict__ csr_src,
        const float* __restrict__ as1, const float* __restrict__ ad1,
        const _Float16* __restrict__ xw1h, const float* __restrict__ b1,
        _Float16* __restrict__ h) {
    int wv = threadIdx.x >> 6, lane = threadIdx.x & 63;
    int n = blockIdx.x * 4 + wv;
    if (n >= N_NODES) return;
    int s = off[n], e = off[n + 1];
    float adn0 = ad1[2 * n], adn1 = ad1[2 * n + 1];
    int e4 = lane >> 4, q = lane & 15;      // edge slot 0..3; cols 8q..8q+7 (q<8:head0)
    float acc[8];
#pragma unroll
    for (int i = 0; i < 8; i++) acc[i] = 0.f;
    float sum0 = 0.f, sum1 = 0.f;
    for (int b = s; b < e; b += 64) {
        int cnt = min(64, e - b);
        int l = lane < cnt ? lane : cnt - 1;
        int srcv = csr_src[b + l];
        float2 a = *(const float2*)&as1[2 * srcv];
        float e0 = a.x + adn0; e0 = e0 > 0.f ? e0 : NEG_SLOPE * e0;
        float e1 = a.y + adn1; e1 = e1 > 0.f ? e1 : NEG_SLOPE * e1;
        float f0v = (lane < cnt) ? __expf(e0) : 0.f;
        float f1v = (lane < cnt) ? __expf(e1) : 0.f;
        float r0 = f0v, r1 = f1v;
#pragma unroll
        for (int m = 32; m >= 1; m >>= 1) { r0 += __shfl_xor(r0, m); r1 += __shfl_xor(r1, m); }
        sum0 += r0; sum1 += r1;
        for (int jj = 0; jj < cnt; jj += 4) {
            int j = jj + e4;
            bool val = j < cnt;
            int sl = val ? j : jj;
            int src = __shfl(srcv, sl);
            float ff0 = __shfl(f0v, sl);
            float ff1 = __shfl(f1v, sl);
            float f = (q >= 8) ? ff1 : ff0;
            if (!val) f = 0.f;
            half8v hv = *(const half8v*)&xw1h[(size_t)src * 128 + 8 * q];
#pragma unroll
            for (int i = 0; i < 8; i++) acc[i] = fmaf((float)hv[i], f, acc[i]);
        }
    }
#pragma unroll
    for (int m = 32; m >= 16; m >>= 1) {
#pragma unroll
        for (int i = 0; i < 8; i++) acc[i] += __shfl_xor(acc[i], m);
    }
    if (lane < 16) {
        float sum = (q >= 8) ? sum1 : sum0;
        int c = 8 * q;
        half8v o;
#pragma unroll
        for (int i = 0; i < 8; i++) {
            float vv = acc[i] / sum + b1[c + i];
            o[i] = (_Float16)(vv > 0.f ? vv : 0.f);   // relu
        }
        *(half8v*)&h[(size_t)n * 128 + c] = o;
    }
}

// ---------------- Layer 2 GEMM: MFMA 16x16x32_f16, fp16 h input, N=64 ---------------

__global__ __launch_bounds__(256) void gemm2_kernel(
        const _Float16* __restrict__ h, const _Float16* __restrict__ W2T,
        const float* __restrict__ att_src2, const float* __restrict__ att_dst2,
        _Float16* __restrict__ xw2h, float* __restrict__ as2, float* __restrict__ ad2) {
    __shared__ _Float16 xs[64 * 136];
    int tid = threadIdx.x;
    int base = blockIdx.x * 64;
#pragma unroll 4
    for (int it = 0; it < 4; ++it) {
        int idx = it * 256 + tid;           // 0..1023 chunks of 8 halves
        int nn = idx >> 4, k8 = idx & 15;
        half8v vv = (half8v)(_Float16)0.f;
        if (base + nn < N_NODES) vv = *(const half8v*)&h[(size_t)(base + nn) * 128 + k8 * 8];
        *(half8v*)&xs[nn * 136 + k8 * 8] = vv;
    }
    __syncthreads();
    int w = tid >> 6, l = tid & 63;
    int quad = l >> 4, lq = l & 15;
    float4v acc[4];
#pragma unroll
    for (int t = 0; t < 4; t++) acc[t] = (float4v)0.f;
    const _Float16* arow = &xs[(16 * w + lq) * 136];
#pragma unroll
    for (int ks = 0; ks < 4; ++ks) {
        half8v a = *(const half8v*)&arow[ks * 32 + quad * 8];
#pragma unroll
        for (int t = 0; t < 4; t++) {
            half8v b = *(const half8v*)&W2T[(t * 16 + lq) * 128 + ks * 32 + quad * 8];
            acc[t] = __builtin_amdgcn_mfma_f32_16x16x32_f16(a, b, acc[t], 0, 0, 0);
        }
    }
    float s_att[4], d_att[4];
#pragma unroll
    for (int t = 0; t < 4; t++) {
        s_att[t] = att_src2[t * 16 + lq];
        d_att[t] = att_dst2[t * 16 + lq];
    }
#pragma unroll
    for (int r = 0; r < 4; r++) {
        float ps = 0.f, pd = 0.f;
#pragma unroll
        for (int t = 0; t < 4; t++) {
            ps = fmaf(acc[t][r], s_att[t], ps);
            pd = fmaf(acc[t][r], d_att[t], pd);
        }
#pragma unroll
        for (int m = 8; m >= 1; m >>= 1) {
            ps += __shfl_xor(ps, m);
            pd += __shfl_xor(pd, m);
        }
        int n = base + 16 * w + quad * 4 + r;
        if (lq == 0 && n < N_NODES) { as2[n] = ps; ad2[n] = pd; }
    }
    __syncthreads();
#pragma unroll
    for (int t = 0; t < 4; t++)
#pragma unroll
        for (int r = 0; r < 4; r++)
            xs[(16 * w + quad * 4 + r) * 72 + t * 16 + lq] = (_Float16)acc[t][r];
    __syncthreads();
#pragma unroll
    for (int it = 0; it < 2; ++it) {
        int idx = it * 256 + tid;           // 0..511
        int node = idx >> 3, k8 = idx & 7;
        if (base + node < N_NODES) {
            half8v vv = *(const half8v*)&xs[node * 72 + k8 * 8];
            *(half8v*)&xw2h[(size_t)(base + node) * 64 + k8 * 8] = vv;
        }
    }
}

// ---- Layer 2 aggregation (r10 structure): 8 edges/iter, fused u/v epilogue ----

__global__ __launch_bounds__(256) void agg2_kernel(
        const int* __restrict__ off, const int* __restrict__ csr_src,
        const float* __restrict__ as2, const float* __restrict__ ad2,
        const _Float16* __restrict__ xw2h, const float* __restrict__ b2,
        const float* __restrict__ lw, float* __restrict__ u, float* __restrict__ v) {
    int wv = threadIdx.x >> 6, lane = threadIdx.x & 63;
    int n = blockIdx.x * 4 + wv;
    if (n >= N_NODES) return;
    int s = off[n], e = off[n + 1];
    float adn = ad2[n];
    int e8 = lane >> 3, q = lane & 7;       // edge slot 0..7; cols 8q..8q+7
    float acc[8];
#pragma unroll
    for (int i = 0; i < 8; i++) acc[i] = 0.f;
    float sum = 0.f;
    for (int b = s; b < e; b += 64) {
        int cnt = min(64, e - b);
        int l = lane < cnt ? lane : cnt - 1;
        int srcv = csr_src[b + l];
        float a = as2[srcv];
        float ev = a + adn; ev = ev > 0.f ? ev : NEG_SLOPE * ev;
        float fv = (lane < cnt) ? __expf(ev) : 0.f;
        float r = fv;
#pragma unroll
        for (int m = 32; m >= 1; m >>= 1) r += __shfl_xor(r, m);
        sum += r;
        for (int jj = 0; jj < cnt; jj += 8) {
            int j = jj + e8;
            bool val = j < cnt;
            int sl = val ? j : jj;
            int src = __shfl(srcv, sl);
            float f = __shfl(fv, sl);
            if (!val) f = 0.f;
            half8v hv = *(const half8v*)&xw2h[(size_t)src * 64 + 8 * q];
#pragma unroll
            for (int i = 0; i < 8; i++) acc[i] = fmaf((float)hv[i], f, acc[i]);
        }
    }
#pragma unroll
    for (int m = 32; m >= 8; m >>= 1) {
#pragma unroll
        for (int i = 0; i < 8; i++) acc[i] += __shfl_xor(acc[i], m);
    }
    int c = 8 * q;
    float pu = 0.f, pv = 0.f;
#pragma unroll
    for (int i = 0; i < 8; i++) {
        float zi = acc[i] / sum + b2[c + i];
        pu = fmaf(zi, lw[c + i], pu);
        pv = fmaf(zi, lw[64 + c + i], pv);
    }
#pragma unroll
    for (int m = 4; m >= 1; m >>= 1) {
        pu += __shfl_xor(pu, m);
        pv += __shfl_xor(pv, m);
    }
    if (lane == 0) { u[n] = pu; v[n] = pv; }
}

// ---------------- Link decode: out = u[s] + v[d] + lb ----------------

__global__ __launch_bounds__(256) void decode_kernel(
        const int* __restrict__ pos_ei, const int* __restrict__ neg_ei,
        const float* __restrict__ u, const float* __restrict__ v,
        const float* __restrict__ lb, float* __restrict__ out) {
    int idx = blockIdx.x * 256 + threadIdx.x;
    if (idx >= 2 * P_CAND) return;
    const int* ei; int p;
    if (idx < P_CAND) { ei = pos_ei; p = idx; }
    else              { ei = neg_ei; p = idx - P_CAND; }
    int sN = ei[p], dN = ei[P_CAND + p];
    out[idx] = u[sN] + v[dN] + lb[0];
}

// ---------------- launch ----------------

extern "C" void kernel_launch(void* const* d_in, const int* in_sizes, int n_in,
                              void* d_out, int out_size, void* d_ws, size_t ws_size,
                              hipStream_t stream) {
    const float* x        = (const float*)d_in[0];
    const int*   ei       = (const int*)d_in[1];
    const int*   pos_ei   = (const int*)d_in[3];
    const int*   neg_ei   = (const int*)d_in[4];
    const float* W1       = (const float*)d_in[5];
    const float* att_src1 = (const float*)d_in[6];
    const float* att_dst1 = (const float*)d_in[7];
    const float* b1       = (const float*)d_in[8];
    const float* W2       = (const float*)d_in[9];
    const float* att_src2 = (const float*)d_in[10];
    const float* att_dst2 = (const float*)d_in[11];
    const float* b2       = (const float*)d_in[12];
    const float* lw       = (const float*)d_in[13];
    const float* lb       = (const float*)d_in[14];
    float* out = (float*)d_out;

    char* ws = (char*)d_ws;
    size_t o = 0;
    auto alloc = [&](size_t bytes) -> char* {
        char* p = ws + o;
        o += (bytes + 511) & ~(size_t)511;
        return p;
    };
    _Float16* xw1h  = (_Float16*)alloc((size_t)N_NODES * 128 * 2);  // reused: xw2h
    _Float16* h     = (_Float16*)alloc((size_t)N_NODES * 128 * 2 + 16384); // +slack for OOB-safe reads
    float*    u     = (float*)alloc((size_t)N_NODES * 4);
    float*    v     = (float*)alloc((size_t)N_NODES * 4);
    float*    as1   = (float*)alloc((size_t)N_NODES * 2 * 4);
    float*    ad1   = (float*)alloc((size_t)N_NODES * 2 * 4);
    float*    as2   = (float*)alloc((size_t)N_NODES * 4);
    float*    ad2   = (float*)alloc((size_t)N_NODES * 4);
    int*      off   = (int*)alloc((size_t)(N_NODES + 1) * 4);
    int*      hist  = (int*)alloc((size_t)NTOT * 4);
    int*      histS = (int*)alloc((size_t)NTOT * 4);
    unsigned* binned= (unsigned*)alloc((size_t)EP * 4);
    int*      csr   = (int*)alloc((size_t)EP * 4);
    _Float16* W1T   = (_Float16*)alloc((size_t)128 * 128 * 2);
    _Float16* W2T   = (_Float16*)alloc((size_t)64 * 128 * 2);
    _Float16* xw2h  = xw1h;    // xw1h dead after agg1

    prep_kernel<<<96, 256, 0, stream>>>(W1, W2, W1T, W2T);
    hist_kernel<<<NB2, 256, 0, stream>>>(ei, hist);
    scan2_kernel<<<1, 1024, 0, stream>>>(hist, histS);
    scatterbin_kernel<<<NB2, 256, 0, stream>>>(ei, histS, binned);
    binsort_kernel<<<NBIN, 1024, 0, stream>>>(binned, histS, off, csr);
    gemm1_kernel<<<(N_NODES + 63) / 64, 256, 0, stream>>>(x, W1T, att_src1, att_dst1, xw1h, as1, ad1);
    agg1_kernel<<<(N_NODES + 3) / 4, 256, 0, stream>>>(off, csr, as1, ad1, xw1h, b1, h);
    gemm2_kernel<<<(N_NODES + 63) / 64, 256, 0, stream>>>(h, W2T, att_src2, att_dst2, xw2h, as2, ad2);
    agg2_kernel<<<(N_NODES + 3) / 4, 256, 0, stream>>>(off, csr, as2, ad2, xw2h, b2, lw, u, v);
    decode_kernel<<<(2 * P_CAND + 255) / 256, 256, 0, stream>>>(pos_ei, neg_ei, u, v, lb, out);
}